// Round 11
// baseline (421.650 us; speedup 1.0000x reference)
//
#include <hip/hip_runtime.h>
#include <hip/hip_bf16.h>
#include <cmath>

// Problem constants
constexpr int Bc = 2, Tc = 4096, Dc = 2048, Hc = 16, HDc = 128;
constexpr int Mrows = Bc * Tc;            // 8192
constexpr int NCHUNK = 32, CHUNK = 128;   // T = NCHUNK * CHUNK
constexpr int BHT = Bc * Hc * Tc;         // 131072

// ---------- small helpers ----------
__device__ __forceinline__ unsigned short f2bf(float x) {
  union { float f; unsigned int u; } v; v.f = x;
  unsigned int r = v.u + 0x7FFFu + ((v.u >> 16) & 1u);  // RNE
  return (unsigned short)(r >> 16);
}
__device__ __forceinline__ float bf2f(unsigned short u) {
  union { unsigned int i; float f; } v; v.i = ((unsigned int)u) << 16;
  return v.f;
}

typedef __attribute__((ext_vector_type(8))) short bf16x8;
typedef __attribute__((ext_vector_type(4))) float f32x4;

__device__ __forceinline__ void gload16(const unsigned short* g, unsigned short* l) {
  __builtin_amdgcn_global_load_lds(
      (const __attribute__((address_space(1))) void*)(const void*)g,
      (__attribute__((address_space(3))) void*)(void*)l,
      16, 0, 0);
}

// ---------- fp32 -> bf16 convert (hidden-states) ----------
__global__ void cvt_bf16(const float* __restrict__ in, unsigned short* __restrict__ outp) {
  size_t i = ((size_t)blockIdx.x * 256 + threadIdx.x) * 4;
  float4 f = *(const float4*)(in + i);
  ushort4 u;
  u.x = f2bf(f.x); u.y = f2bf(f.y); u.z = f2bf(f.z); u.w = f2bf(f.w);
  *(ushort4*)(outp + i) = u;
}

// ---------- dst += src (bf16, vectorized) ----------
__global__ void add_bf16(unsigned short* __restrict__ dst, const unsigned short* __restrict__ src) {
  size_t i = ((size_t)blockIdx.x * 256 + threadIdx.x) * 8;
  bf16x8 a = *(const bf16x8*)(dst + i);
  bf16x8 b = *(const bf16x8*)(src + i);
#pragma unroll
  for (int j = 0; j < 8; ++j)
    a[j] = (short)f2bf(bf2f((unsigned short)a[j]) + bf2f((unsigned short)b[j]));
  *(bf16x8*)(dst + i) = a;
}

// ---------- fused weight prep: z0..3 transpose+cvt, z4..5 plain cvt ----------
__global__ void prep6(const float* __restrict__ W0, unsigned short* __restrict__ T0,
                      const float* __restrict__ W1, unsigned short* __restrict__ T1,
                      const float* __restrict__ W2, unsigned short* __restrict__ T2,
                      const float* __restrict__ W3, unsigned short* __restrict__ T3,
                      const float* __restrict__ C4, unsigned short* __restrict__ O4,
                      const float* __restrict__ C5, unsigned short* __restrict__ O5) {
  const int z = blockIdx.z;
  const int n0 = blockIdx.x * 32, k0 = blockIdx.y * 32;
  const int tx = threadIdx.x & 31, ty = threadIdx.x >> 5;  // ty: 0..7
  if (z >= 4) {
    const float* in = (z == 4) ? C4 : C5;
    unsigned short* op = (z == 4) ? O4 : O5;
#pragma unroll
    for (int i = 0; i < 4; ++i) {
      size_t idx = (size_t)(k0 + ty + 8 * i) * Dc + n0 + tx;
      op[idx] = f2bf(in[idx]);
    }
    return;
  }
  const float* W; unsigned short* Wt;
  switch (z) {
    case 0: W = W0; Wt = T0; break;
    case 1: W = W1; Wt = T1; break;
    case 2: W = W2; Wt = T2; break;
    default: W = W3; Wt = T3; break;
  }
  __shared__ float tile[32][33];
#pragma unroll
  for (int i = 0; i < 4; ++i)
    tile[ty + 8 * i][tx] = W[(size_t)(k0 + ty + 8 * i) * Dc + n0 + tx];
  __syncthreads();
#pragma unroll
  for (int i = 0; i < 4; ++i)
    Wt[(size_t)(n0 + ty + 8 * i) * Dc + k0 + tx] = f2bf(tile[tx][ty + 8 * i]);
}

// ============================================================================
// Barrier-light ring-4 GEMM (champion structure + micro-pipelined staging):
//   C[M,N] = A[M,K](bf16, lda) * Bt[N,K](bf16)^T, K hardcoded 2048, BK=32.
// LDS ring of 4 buffers, staged 3 tiles ahead via global_load_lds. ONE
// vmcnt(8) + ONE s_barrier per K-tile. The 4 staging gloads and the 12 frag
// ds_reads are spread through the two 16-MFMA half-clusters so LDS-write,
// VMEM-issue, ds_read and MFMA traffic interleave instead of bursting.
// XOR bank-conflict swizzle (0 conflicts verified): pre-swizzled global
// source for staging (LDS dest linear) + swizzle folded into per-lane reads.
// EPI: 0 = fp32 store, 1 = bf16 store,
//      5 = fused SKV (N=6144): seg0 = S: exp(acc+2*eoff) row-reduced over the
//          wave's 64 cols -> per-head partial dots into C0 (dotP[2][BH*T]),
//          NO C store; seg1 = exp(acc+eoff)->C1 (K'); seg2 = plain->C2 (V).
// z-batch: blockIdx.y==1 switches to (A1,B1,C1a) (weight-pair use).
// ============================================================================
template <int EPI, int WMw, int WNw, int MI, int NI>
__global__ __launch_bounds__(WMw * WNw * 64, 2) void gemmL(
    const unsigned short* __restrict__ A0, const unsigned short* __restrict__ B0,
    void* __restrict__ C0, void* __restrict__ C1, void* __restrict__ C2,
    const unsigned short* __restrict__ A1, const unsigned short* __restrict__ B1,
    void* __restrict__ C1a,
    int M, int N, int lda, int ldc, float eoff) {
  constexpr int K = 2048;
  constexpr int NT = K / 32;                 // 64 K-tiles
  constexpr int THREADS = WMw * WNw * 64;
  constexpr int BM = WMw * MI * 16;
  constexpr int BN = WNw * NI * 16;
  constexpr int ASLAB = BM * 32;             // elems per A K-slab
  constexpr int BSLAB = BN * 32;
  constexpr int BUF = ASLAB + BSLAB;
  constexpr int SROWS = THREADS / 4;         // rows staged per gload pass
  static_assert(2 * SROWS == BM && BM == BN, "staging geometry");
  extern __shared__ unsigned short lds[];    // 4 * BUF elems

  const unsigned short* A = A0;
  const unsigned short* Bt = B0;
  void* Cz = C0;
  if (blockIdx.y) { A = A1; Bt = B1; Cz = C1a; }

  const int tid = threadIdx.x;
  const int lane = tid & 63;
  const int wave = tid >> 6;
  const int wm = wave / WNw;
  const int wn = wave % WNw;

  const int nbn = N / BN;
  const int nwg = (M / BM) * nbn;
  const int bidx = (int)blockIdx.x;
  const int wgid = (bidx & 7) * (nwg >> 3) + (bidx >> 3);  // XCD swizzle (nwg%8==0)
  const int bm = wgid / nbn;
  const int bn = wgid % nbn;

  // ---- staging: slab = BM rows x 32 bf16 (64B rows), 2 gloads per slab
  const int srow = tid >> 2;                    // 0..SROWS-1
  const int scolL = (tid & 3) << 3;             // linear LDS col (elems)
  const int scolG = scolL ^ ((srow & 6) << 2);  // pre-swizzled global source col
  const unsigned short* gA = A + (size_t)(bm * BM + srow) * lda + scolG;
  const unsigned short* gB = Bt + (size_t)(bn * BN + srow) * K + scolG;
  const int sstage = srow * 32 + scolL;         // LDS elem offset (linear dest)
  const size_t arstep = (size_t)SROWS * lda;
  const size_t brstep = (size_t)SROWS * K;

  // ---- fragment read offsets (swizzle folded per-lane)
  const int fr = lane & 15;
  const int fko = ((lane >> 4) << 3) ^ ((lane & 6) << 2);
  const int aoff = (wm * MI * 16 + fr) * 32 + fko;            // + mi*512
  const int boff = ASLAB + (wn * NI * 16 + fr) * 32 + fko;    // + ni*512

  f32x4 acc[MI][NI] = {};

  // ---- prologue: stage tiles 0,1,2 into slots 0,1,2 (12 gloads)
#pragma unroll
  for (int t = 0; t < 3; ++t) {
    const unsigned short* sA = gA + t * 32;
    const unsigned short* sB = gB + t * 32;
    unsigned short* dst = lds + t * BUF;
    gload16(sA,          dst + sstage);
    gload16(sA + arstep, dst + sstage + SROWS * 32);
    gload16(sB,          dst + ASLAB + sstage);
    gload16(sB + brstep, dst + ASLAB + sstage + SROWS * 32);
  }
  asm volatile("s_waitcnt vmcnt(8)" ::: "memory");  // tile 0 landed
  __builtin_amdgcn_s_barrier();

  for (int v = 0; v < NT; ++v) {
    const int rb = (v & 3) * BUF;            // read slot
    const int wb = ((v + 3) & 3) * BUF;      // stage slot (tile v+3)
    const int tn = (v + 3) & (NT - 1);       // wrap-stage near tail: harmless
    const unsigned short* srcA = gA + tn * 32;
    const unsigned short* srcB = gB + tn * 32;

    bf16x8 af[MI], bfv[NI];
#pragma unroll
    for (int ni = 0; ni < NI; ++ni)
      bfv[ni] = *(const bf16x8*)(lds + rb + boff + ni * 512);
#pragma unroll
    for (int mi = 0; mi < MI / 2; ++mi)
      af[mi] = *(const bf16x8*)(lds + rb + aoff + mi * 512);

    gload16(srcA, lds + wb + sstage);        // stage A half 1 (tile v+3)

    __builtin_amdgcn_s_setprio(1);
#pragma unroll
    for (int mi = 0; mi < MI / 2; ++mi)
#pragma unroll
      for (int ni = 0; ni < NI; ++ni)
        acc[mi][ni] = __builtin_amdgcn_mfma_f32_16x16x32_bf16(af[mi], bfv[ni], acc[mi][ni], 0, 0, 0);
    __builtin_amdgcn_s_setprio(0);

#pragma unroll
    for (int mi = MI / 2; mi < MI; ++mi)
      af[mi] = *(const bf16x8*)(lds + rb + aoff + mi * 512);
    gload16(srcA + arstep, lds + wb + sstage + SROWS * 32);   // stage A half 2
    gload16(srcB,          lds + wb + ASLAB + sstage);        // stage B half 1

    __builtin_amdgcn_s_setprio(1);
#pragma unroll
    for (int mi = MI / 2; mi < MI; ++mi)
#pragma unroll
      for (int ni = 0; ni < NI; ++ni)
        acc[mi][ni] = __builtin_amdgcn_mfma_f32_16x16x32_bf16(af[mi], bfv[ni], acc[mi][ni], 0, 0, 0);
    __builtin_amdgcn_s_setprio(0);

    gload16(srcB + brstep, lds + wb + ASLAB + sstage + SROWS * 32);  // stage B half 2

    // one counted wait + one barrier per tile: tile v+1 landed for all waves
    asm volatile("s_waitcnt vmcnt(8)" ::: "memory");
    __builtin_amdgcn_s_barrier();
  }

  // ---- epilogue
  const int fq = lane >> 4;
  const int crow = bm * BM + wm * (MI * 16);
  if constexpr (EPI == 5) {
    const int seg = bn >> 3;  // 0:S(dot) 1:K' 2:V   (BN=256, 8 col-blocks/seg)
    if (seg == 0) {
      // row-sum of exp(S + 2*eoff) over this wave's 64 cols
      float s2[MI][4];
#pragma unroll
      for (int mi = 0; mi < MI; ++mi)
#pragma unroll
        for (int ii = 0; ii < 4; ++ii) {
          float t = 0.f;
#pragma unroll
          for (int ni = 0; ni < NI; ++ni)
            t += __expf(acc[mi][ni][ii] + 2.f * eoff);
          s2[mi][ii] = t;
        }
      // reduce over fr (lane bits 0..3); all 16 lanes end with the full sum
#pragma unroll
      for (int m = 1; m < 16; m <<= 1)
#pragma unroll
        for (int mi = 0; mi < MI; ++mi)
#pragma unroll
          for (int ii = 0; ii < 4; ++ii)
            s2[mi][ii] += __shfl_xor(s2[mi][ii], m);
      // head & partial-id; each lane stores 2 of the wave's 128 row-sums
      const int h = (bn & 7) * 2 + (wn >> 1);
      const int part = wn & 1;
      float* dp = (float*)C0 + (size_t)part * BHT;
#pragma unroll
      for (int u = 0; u < 2; ++u) {
        const int idx = fr * 2 + u;            // 0..31
        const int mi = idx >> 2, ii = idx & 3;
        const int r = crow + mi * 16 + fq * 4 + ii;
        const int b = r >> 12, t = r & (Tc - 1);
        dp[((size_t)(b * Hc + h)) * Tc + t] = s2[mi][ii];
      }
    } else {
      unsigned short* outp = (unsigned short*)(seg == 1 ? C1 : C2);
      const int ccol = (bn & 7) * BN + wn * (NI * 16) + fr;
#pragma unroll
      for (int mi = 0; mi < MI; ++mi)
#pragma unroll
        for (int ni = 0; ni < NI; ++ni)
#pragma unroll
          for (int ii = 0; ii < 4; ++ii) {
            const int r = crow + mi * 16 + fq * 4 + ii;
            const int c = ccol + ni * 16;
            float vv = acc[mi][ni][ii];
            if (seg == 1) vv = __expf(vv + eoff);
            outp[(size_t)r * ldc + c] = f2bf(vv);
          }
    }
  } else {
    const int ccol = bn * BN + wn * (NI * 16) + fr;
#pragma unroll
    for (int mi = 0; mi < MI; ++mi)
#pragma unroll
      for (int ni = 0; ni < NI; ++ni)
#pragma unroll
        for (int ii = 0; ii < 4; ++ii) {
          const int r = crow + mi * 16 + fq * 4 + ii;
          const int c = ccol + ni * 16;
          const size_t idx = (size_t)r * ldc + c;
          float vv = acc[mi][ni][ii];
          if (EPI == 0) ((float*)Cz)[idx] = vv;
          else          ((unsigned short*)Cz)[idx] = f2bf(vv);
        }
  }
}

// ---------- combine dot partials + per-chunk V sums (raw sums to chks) ----------
__global__ void scan_chunks2(const float* __restrict__ dotP,
                             const unsigned short* __restrict__ v,
                             float* __restrict__ dotb,
                             float* __restrict__ chks) {
  __shared__ float dt[CHUNK];
  const int bid = blockIdx.x;          // bh*NCHUNK + c
  const int c = bid & (NCHUNK - 1);
  const int bh = bid >> 5;
  const int b = bh >> 4, h = bh & 15;
  const int d = threadIdx.x;           // 128
  const int t0 = c * CHUNK;

  const size_t di = (size_t)bh * Tc + t0 + d;
  float dv = dotP[di] + dotP[(size_t)BHT + di];
  dt[d] = dv;
  dotb[di] = dv;
  __syncthreads();

  const unsigned short* vp = v + ((size_t)(b * Tc + t0)) * Dc + h * HDc + d;
  float acc = 0.f;
  for (int t = 0; t < CHUNK; ++t)
    acc += dt[t] * bf2f(vp[(size_t)t * Dc]);
  chks[(size_t)bid * HDc + d] = acc;
}

// ---------- final: exclusive prefix of chunk sums (in-block) + cumsum/divide ----
__global__ void scan_final(const float* __restrict__ dotb,
                           const unsigned short* __restrict__ v,
                           const unsigned short* __restrict__ kp,
                           const float* __restrict__ chks,
                           unsigned short* __restrict__ attn) {
  int bid = blockIdx.x;
  int c = bid % NCHUNK, bh = bid / NCHUNK;
  int b = bh / Hc, h = bh % Hc;
  int d = threadIdx.x;
  // exclusive prefix over preceding chunks (same order as the old scan_offsets)
  float acc = 0.f;
  for (int cc = 0; cc < c; ++cc)
    acc += chks[((size_t)bh * NCHUNK + cc) * HDc + d];
  const float* dp = dotb + (size_t)bh * Tc + c * CHUNK;
  size_t base = ((size_t)(b * Tc + c * CHUNK)) * Dc + h * HDc + d;
  for (int t = 0; t < CHUNK; ++t) {
    size_t idx = base + (size_t)t * Dc;
    acc += dp[t] * bf2f(v[idx]);
    attn[idx] = f2bf(acc / bf2f(kp[idx]));
  }
}

// ---------- launch ----------
extern "C" void kernel_launch(void* const* d_in, const int* in_sizes, int n_in,
                              void* d_out, int out_size, void* d_ws, size_t ws_size,
                              hipStream_t stream) {
  const float* hs = (const float*)d_in[0];
  const float* Wq = (const float*)d_in[1];
  const float* Wk = (const float*)d_in[2];
  const float* Wv = (const float*)d_in[3];
  const float* Wo = (const float*)d_in[4];
  const float* Fq = (const float*)d_in[5];
  const float* Fk = (const float*)d_in[6];
  float* out = (float*)d_out;

  const size_t MD = (size_t)Mrows * Dc;  // 16,777,216
  const size_t DD = (size_t)Dc * Dc;     // 4,194,304

  char* w = (char*)d_ws;
  size_t off = 0;
  auto take = [&](size_t bytes) -> void* {
    void* r = w + off;
    off += (bytes + 255) & ~(size_t)255;
    return r;
  };

  unsigned short* hs_bf = (unsigned short*)take(MD * 2);  // reused as attnbf
  unsigned short* wq_bf = (unsigned short*)take(DD * 2);
  unsigned short* wtfq  = (unsigned short*)take(DD * 2);
  unsigned short* wk_bf = (unsigned short*)take(DD * 2);
  unsigned short* wtfk  = (unsigned short*)take(DD * 2);
  unsigned short* wcat  = (unsigned short*)take(3 * DD * 2);  // [Wsum^T|Wkf^T|Wv^T]
  unsigned short* wto   = (unsigned short*)take(DD * 2);
  unsigned short* Kp    = (unsigned short*)take(MD * 2);
  unsigned short* Vbf   = (unsigned short*)take(MD * 2);
  float* dotP = (float*)take((size_t)2 * BHT * 4);            // per-head dot partials
  float* dotb = (float*)take((size_t)BHT * 4);
  float* chks = (float*)take((size_t)Bc * Hc * NCHUNK * HDc * 4);

  // alias (stream-ordered reuse): hs_bf dead after fused SKV GEMM
  unsigned short* attnbf = hs_bf;

  const float OFF = (float)(-0.5 * log(2048.0) + 1e-6);

  // allow dynamic LDS (defensive; ignore errors)
  (void)hipFuncSetAttribute((const void*)gemmL<0, 2, 4, 8, 4>, hipFuncAttributeMaxDynamicSharedMemorySize, 131072);
  (void)hipFuncSetAttribute((const void*)gemmL<5, 2, 4, 8, 4>, hipFuncAttributeMaxDynamicSharedMemorySize, 131072);
  (void)hipFuncSetAttribute((const void*)gemmL<1, 2, 2, 4, 4>, hipFuncAttributeMaxDynamicSharedMemorySize, 65536);

  // 1) convert hidden states
  cvt_bf16<<<(int)(MD / 1024), 256, 0, stream>>>(hs, hs_bf);

  // 2) fused weight prep: transposes (Fq,Fk,Wv,Wo) + plain cvts (Wq,Wk)
  prep6<<<dim3(Dc / 32, Dc / 32, 6), 256, 0, stream>>>(
      Fq, wtfq, Fk, wtfk, Wv, wcat + 2 * DD, Wo, wto, Wq, wq_bf, Wk, wk_bf);

  // 3) weight products (z-batched, 128^2 tiles, ring-4 = 64KB LDS):
  //    wcat[0:DD) = (Wq@Fq)^T ; wcat[DD:2DD) = (Wk@Fk)^T
  gemmL<1, 2, 2, 4, 4><<<dim3(256, 2), 256, 65536, stream>>>(
      wtfq, wq_bf, wcat, nullptr, nullptr,
      wtfk, wk_bf, wcat + DD,
      2048, 2048, 2048, 2048, 0.f);

  // 3b) Wsum^T = Wqf^T + Wkf^T (in place over wcat[0:DD))
  add_bf16<<<(int)(DD / 2048), 256, 0, stream>>>(wcat, wcat + DD);

  // 4) fused SKV GEMM: hs @ [Wsum|Wkf|Wv] ->
  //    seg0: per-head dot partials (dotP), seg1: K'=exp (Kp), seg2: V (Vbf)
  const int fblocks = (Mrows / 256) * (6144 / 256);  // 768
  gemmL<5, 2, 4, 8, 4><<<fblocks, 512, 131072, stream>>>(
      hs_bf, wcat, dotP, Kp, Vbf, nullptr, nullptr, nullptr,
      Mrows, 6144, Dc, Dc, OFF);

  // 5) combine dot partials + per-chunk V sums (raw chunk sums)
  scan_chunks2<<<Bc * Hc * NCHUNK, 128, 0, stream>>>(dotP, Vbf, dotb, chks);

  // 6) final: in-block exclusive prefix + cumsum + divide -> bf16 attn
  scan_final<<<Bc * Hc * NCHUNK, 128, 0, stream>>>(dotb, Vbf, Kp, chks, attnbf);

  // 7) output projection (fp32 out)
  const int gblocks = (Mrows / 256) * (Dc / 256);  // 256
  gemmL<0, 2, 4, 8, 4><<<gblocks, 512, 131072, stream>>>(
      attnbf, wto, out, nullptr, nullptr, nullptr, nullptr, nullptr,
      Mrows, Dc, Dc, Dc, 0.f);
}

// Round 12
// 421.317 us; speedup vs baseline: 1.0008x; 1.0008x over previous
//
#include <hip/hip_runtime.h>
#include <hip/hip_bf16.h>
#include <cmath>

// Problem constants
constexpr int Bc = 2, Tc = 4096, Dc = 2048, Hc = 16, HDc = 128;
constexpr int Mrows = Bc * Tc;            // 8192
constexpr int NCHUNK = 32, CHUNK = 128;   // T = NCHUNK * CHUNK
constexpr int BHT = Bc * Hc * Tc;         // 131072

// ---------- small helpers ----------
__device__ __forceinline__ unsigned short f2bf(float x) {
  union { float f; unsigned int u; } v; v.f = x;
  unsigned int r = v.u + 0x7FFFu + ((v.u >> 16) & 1u);  // RNE
  return (unsigned short)(r >> 16);
}
__device__ __forceinline__ float bf2f(unsigned short u) {
  union { unsigned int i; float f; } v; v.i = ((unsigned int)u) << 16;
  return v.f;
}

typedef __attribute__((ext_vector_type(8))) short bf16x8;
typedef __attribute__((ext_vector_type(4))) float f32x4;

__device__ __forceinline__ void gload16(const unsigned short* g, unsigned short* l) {
  __builtin_amdgcn_global_load_lds(
      (const __attribute__((address_space(1))) void*)(const void*)g,
      (__attribute__((address_space(3))) void*)(void*)l,
      16, 0, 0);
}

// ---------- fp32 -> bf16 convert (hidden-states) ----------
__global__ void cvt_bf16(const float* __restrict__ in, unsigned short* __restrict__ outp) {
  size_t i = ((size_t)blockIdx.x * 256 + threadIdx.x) * 4;
  float4 f = *(const float4*)(in + i);
  ushort4 u;
  u.x = f2bf(f.x); u.y = f2bf(f.y); u.z = f2bf(f.z); u.w = f2bf(f.w);
  *(ushort4*)(outp + i) = u;
}

// ---------- dst += src (bf16, vectorized) ----------
__global__ void add_bf16(unsigned short* __restrict__ dst, const unsigned short* __restrict__ src) {
  size_t i = ((size_t)blockIdx.x * 256 + threadIdx.x) * 8;
  bf16x8 a = *(const bf16x8*)(dst + i);
  bf16x8 b = *(const bf16x8*)(src + i);
#pragma unroll
  for (int j = 0; j < 8; ++j)
    a[j] = (short)f2bf(bf2f((unsigned short)a[j]) + bf2f((unsigned short)b[j]));
  *(bf16x8*)(dst + i) = a;
}

// ---------- fused weight prep: z0..3 transpose+cvt, z4..5 plain cvt ----------
__global__ void prep6(const float* __restrict__ W0, unsigned short* __restrict__ T0,
                      const float* __restrict__ W1, unsigned short* __restrict__ T1,
                      const float* __restrict__ W2, unsigned short* __restrict__ T2,
                      const float* __restrict__ W3, unsigned short* __restrict__ T3,
                      const float* __restrict__ C4, unsigned short* __restrict__ O4,
                      const float* __restrict__ C5, unsigned short* __restrict__ O5) {
  const int z = blockIdx.z;
  const int n0 = blockIdx.x * 32, k0 = blockIdx.y * 32;
  const int tx = threadIdx.x & 31, ty = threadIdx.x >> 5;  // ty: 0..7
  if (z >= 4) {
    const float* in = (z == 4) ? C4 : C5;
    unsigned short* op = (z == 4) ? O4 : O5;
#pragma unroll
    for (int i = 0; i < 4; ++i) {
      size_t idx = (size_t)(k0 + ty + 8 * i) * Dc + n0 + tx;
      op[idx] = f2bf(in[idx]);
    }
    return;
  }
  const float* W; unsigned short* Wt;
  switch (z) {
    case 0: W = W0; Wt = T0; break;
    case 1: W = W1; Wt = T1; break;
    case 2: W = W2; Wt = T2; break;
    default: W = W3; Wt = T3; break;
  }
  __shared__ float tile[32][33];
#pragma unroll
  for (int i = 0; i < 4; ++i)
    tile[ty + 8 * i][tx] = W[(size_t)(k0 + ty + 8 * i) * Dc + n0 + tx];
  __syncthreads();
#pragma unroll
  for (int i = 0; i < 4; ++i)
    Wt[(size_t)(n0 + ty + 8 * i) * Dc + k0 + tx] = f2bf(tile[tx][ty + 8 * i]);
}

// ============================================================================
// gemm8 — m201-faithful 8-phase-per-2-tiles GEMM, 256x256 tile, 8 waves:
//   C[M,N] = A[M,K](bf16, lda) * Bt[N,K](bf16)^T, K hardcoded 2048.
// BK=64 tiles stored as 4 slabs (Ak0,Ak1,Bk0,Bk1; each 256 rows x 32 k,
// 16 KB), double-buffered (2 x 32768 elems = 128 KiB LDS).
// 4 phases per tile = quadrants (kk x mi-half), 16 MFMA each:
//   {ds_read 4-8 x b128; stage ONE slab of tile v+1 (2 gloads); barrier;
//    lgkmcnt(0); setprio(1); 16 MFMA; setprio(0); [vmcnt(4) q1/q3]; barrier}
// vmcnt(4) FIFO ledger (issue order Ak0,Bk0,Ak1,Bk1 per tile): at q1-end,
// outstanding = {Ak1(v),Bk1(v),Ak0(v+1),Bk0(v+1)}=8 -> drains Ak1,Bk1(v)
// needed at q2; at q3-end drains Ak0,Bk0(v+1) needed at next q0. Always 2
// slabs in flight with 2 phases of slack; never a drain-to-0.
// XOR bank-conflict swizzle (0 conflicts verified): pre-swizzled global
// source (LDS dest linear, as global_load_lds requires) + folded into reads.
// EPI: 0 = fp32 store,
//      5 = fused SKV (N=6144): seg0 = S: exp(acc+2*eoff) row-reduced over
//          wave's 64 cols -> per-head partial dots (C0 = dotP[2][BH*T]);
//          seg1 = exp(acc+eoff)->C1 (K'); seg2 = plain->C2 (V).
// ============================================================================
template <int EPI>
__global__ __launch_bounds__(512, 2) void gemm8(
    const unsigned short* __restrict__ A,
    const unsigned short* __restrict__ Bt,
    void* __restrict__ C0, void* __restrict__ C1, void* __restrict__ C2,
    int M, int N, int lda, int ldc, float eoff) {
  constexpr int K = 2048;
  constexpr int NT = K / 64;                 // 32 BK=64 tiles
  extern __shared__ unsigned short lds[];    // 65536 elems = 128 KiB

  const int tid = threadIdx.x;
  const int lane = tid & 63;
  const int wave = tid >> 6;
  const int wm = wave >> 2;    // 0..1
  const int wn = wave & 3;     // 0..3

  const int nbn = N >> 8;
  const int nwg = (M >> 8) * nbn;
  const int bidx = (int)blockIdx.x;
  const int wgid = (bidx & 7) * (nwg >> 3) + (bidx >> 3);  // XCD swizzle (nwg%8==0)
  const int bm = wgid / nbn;
  const int bn = wgid % nbn;

  // ---- staging: slab = 256 rows x 32 k (64B rows), 2 gload passes
  const int srow = tid >> 2;                    // 0..127
  const int scolL = (tid & 3) << 3;
  const int scolG = scolL ^ ((srow & 6) << 2);  // pre-swizzled global source col
  const unsigned short* gA = A + (size_t)(bm * 256 + srow) * lda + scolG;
  const unsigned short* gB = Bt + (size_t)(bn * 256 + srow) * K + scolG;
  const int sstage = srow * 32 + scolL;
  const size_t arstep = (size_t)128 * lda;
  const size_t brstep = (size_t)128 * K;

  // ---- fragment read offsets (swizzle folded per-lane)
  const int fr = lane & 15;
  const int fko = ((lane >> 4) << 3) ^ ((lane & 6) << 2);
  const int aoff = (wm * 128 + fr) * 32 + fko;            // +mi*512, +kk*8192
  const int boff = 16384 + (wn * 64 + fr) * 32 + fko;     // +ni*512, +kk*8192

  f32x4 acc[8][4] = {};

  // ---- prologue: tile 0 into buf0, issue order Ak0, Bk0, Ak1, Bk1
  gload16(gA,               lds + sstage);
  gload16(gA + arstep,      lds + sstage + 4096);
  gload16(gB,               lds + 16384 + sstage);
  gload16(gB + brstep,      lds + 16384 + sstage + 4096);
  gload16(gA + 32,          lds + 8192 + sstage);
  gload16(gA + 32 + arstep, lds + 8192 + sstage + 4096);
  gload16(gB + 32,          lds + 24576 + sstage);
  gload16(gB + 32 + brstep, lds + 24576 + sstage + 4096);
  asm volatile("s_waitcnt vmcnt(4)" ::: "memory");  // Ak0,Bk0 landed
  __builtin_amdgcn_s_barrier();

#define PH_MFMA(MOFF)                                                         \
  __builtin_amdgcn_s_barrier();                                               \
  asm volatile("s_waitcnt lgkmcnt(0)" ::: "memory");                          \
  __builtin_amdgcn_s_setprio(1);                                              \
  _Pragma("unroll")                                                           \
  for (int mi = 0; mi < 4; ++mi)                                              \
    _Pragma("unroll")                                                         \
    for (int ni = 0; ni < 4; ++ni)                                            \
      acc[(MOFF) + mi][ni] = __builtin_amdgcn_mfma_f32_16x16x32_bf16(         \
          af[mi], bfv[ni], acc[(MOFF) + mi][ni], 0, 0, 0);                    \
  __builtin_amdgcn_s_setprio(0);

#define TILE8(RB, WB, TN)                                                     \
  {                                                                           \
    const unsigned short* sA = gA + (TN) * 64;                                \
    const unsigned short* sB = gB + (TN) * 64;                                \
    bf16x8 af[4], bfv[4];                                                     \
    /* q0: kk0, mi 0-3 (8 reads); stage Ak0(v+1) */                           \
    _Pragma("unroll")                                                         \
    for (int mi = 0; mi < 4; ++mi)                                            \
      af[mi] = *(const bf16x8*)(lds + (RB) + aoff + mi * 512);                \
    _Pragma("unroll")                                                         \
    for (int ni = 0; ni < 4; ++ni)                                            \
      bfv[ni] = *(const bf16x8*)(lds + (RB) + boff + ni * 512);               \
    gload16(sA,          lds + (WB) + sstage);                                \
    gload16(sA + arstep, lds + (WB) + sstage + 4096);                         \
    PH_MFMA(0)                                                                \
    __builtin_amdgcn_s_barrier();                                             \
    /* q1: kk0, mi 4-7 (4 reads, bfv reused); stage Bk0(v+1) */               \
    _Pragma("unroll")                                                         \
    for (int mi = 0; mi < 4; ++mi)                                            \
      af[mi] = *(const bf16x8*)(lds + (RB) + aoff + (4 + mi) * 512);          \
    gload16(sB,          lds + (WB) + 16384 + sstage);                        \
    gload16(sB + brstep, lds + (WB) + 16384 + sstage + 4096);                 \
    PH_MFMA(4)                                                                \
    asm volatile("s_waitcnt vmcnt(4)" ::: "memory"); /* Ak1,Bk1(v) landed */  \
    __builtin_amdgcn_s_barrier();                                             \
    /* q2: kk1, mi 0-3 (8 reads); stage Ak1(v+1) */                           \
    _Pragma("unroll")                                                         \
    for (int mi = 0; mi < 4; ++mi)                                            \
      af[mi] = *(const bf16x8*)(lds + (RB) + 8192 + aoff + mi * 512);         \
    _Pragma("unroll")                                                         \
    for (int ni = 0; ni < 4; ++ni)                                            \
      bfv[ni] = *(const bf16x8*)(lds + (RB) + 8192 + boff + ni * 512);        \
    gload16(sA + 32,          lds + (WB) + 8192 + sstage);                    \
    gload16(sA + 32 + arstep, lds + (WB) + 8192 + sstage + 4096);             \
    PH_MFMA(0)                                                                \
    __builtin_amdgcn_s_barrier();                                             \
    /* q3: kk1, mi 4-7 (4 reads); stage Bk1(v+1) */                           \
    _Pragma("unroll")                                                         \
    for (int mi = 0; mi < 4; ++mi)                                            \
      af[mi] = *(const bf16x8*)(lds + (RB) + 8192 + aoff + (4 + mi) * 512);   \
    gload16(sB + 32,          lds + (WB) + 24576 + sstage);                   \
    gload16(sB + 32 + brstep, lds + (WB) + 24576 + sstage + 4096);            \
    PH_MFMA(4)                                                                \
    asm volatile("s_waitcnt vmcnt(4)" ::: "memory"); /* Ak0,Bk0(v+1) landed */\
    __builtin_amdgcn_s_barrier();                                             \
  }

  for (int vv = 0; vv < NT; vv += 2) {
    TILE8(0,     32768, vv + 1)
    TILE8(32768, 0,     (vv + 2) & (NT - 1))   // wrap-stage at tail: harmless
  }
#undef TILE8
#undef PH_MFMA

  // ---- epilogue
  const int fq = lane >> 4;
  const int crow = bm * 256 + wm * 128;
  if constexpr (EPI == 5) {
    const int seg = bn >> 3;  // 0:S(dot) 1:K' 2:V   (BN=256, 8 col-blocks/seg)
    if (seg == 0) {
      float s2[8][4];
#pragma unroll
      for (int mi = 0; mi < 8; ++mi)
#pragma unroll
        for (int ii = 0; ii < 4; ++ii) {
          float t = 0.f;
#pragma unroll
          for (int ni = 0; ni < 4; ++ni)
            t += __expf(acc[mi][ni][ii] + 2.f * eoff);
          s2[mi][ii] = t;
        }
#pragma unroll
      for (int m = 1; m < 16; m <<= 1)
#pragma unroll
        for (int mi = 0; mi < 8; ++mi)
#pragma unroll
          for (int ii = 0; ii < 4; ++ii)
            s2[mi][ii] += __shfl_xor(s2[mi][ii], m);
      const int h = (bn & 7) * 2 + (wn >> 1);
      const int part = wn & 1;
      float* dp = (float*)C0 + (size_t)part * BHT;
#pragma unroll
      for (int u = 0; u < 2; ++u) {
        const int idx = fr * 2 + u;            // 0..31
        const int mi = idx >> 2, ii = idx & 3;
        const int r = crow + mi * 16 + fq * 4 + ii;
        const int b = r >> 12, t = r & (Tc - 1);
        dp[((size_t)(b * Hc + h)) * Tc + t] = s2[mi][ii];
      }
    } else {
      unsigned short* outp = (unsigned short*)(seg == 1 ? C1 : C2);
      const int ccol = (bn & 7) * 256 + wn * 64 + fr;
#pragma unroll
      for (int mi = 0; mi < 8; ++mi)
#pragma unroll
        for (int ni = 0; ni < 4; ++ni)
#pragma unroll
          for (int ii = 0; ii < 4; ++ii) {
            const int r = crow + mi * 16 + fq * 4 + ii;
            const int c = ccol + ni * 16;
            float vv = acc[mi][ni][ii];
            if (seg == 1) vv = __expf(vv + eoff);
            outp[(size_t)r * ldc + c] = f2bf(vv);
          }
    }
  } else {
    const int ccol = bn * 256 + wn * 64 + fr;
#pragma unroll
    for (int mi = 0; mi < 8; ++mi)
#pragma unroll
      for (int ni = 0; ni < 4; ++ni)
#pragma unroll
        for (int ii = 0; ii < 4; ++ii) {
          const int r = crow + mi * 16 + fq * 4 + ii;
          const int c = ccol + ni * 16;
          ((float*)C0)[(size_t)r * ldc + c] = acc[mi][ni][ii];
        }
  }
}

// ============================================================================
// Barrier-light ring-4 GEMM (kept for the weight pair; bf16-out only).
// ============================================================================
__global__ __launch_bounds__(256, 2) void gemmW(
    const unsigned short* __restrict__ A0, const unsigned short* __restrict__ B0,
    unsigned short* __restrict__ C0,
    const unsigned short* __restrict__ A1, const unsigned short* __restrict__ B1,
    unsigned short* __restrict__ C1) {
  constexpr int K = 2048, N = 2048;
  constexpr int NT = K / 32;
  constexpr int BM = 128, BN = 128;
  constexpr int ASLAB = BM * 32, BSLAB = BN * 32, BUF = ASLAB + BSLAB;
  constexpr int SROWS = 64;
  extern __shared__ unsigned short lds[];    // 4 * BUF

  const unsigned short* A = blockIdx.y ? A1 : A0;
  const unsigned short* Bt = blockIdx.y ? B1 : B0;
  unsigned short* C = blockIdx.y ? C1 : C0;

  const int tid = threadIdx.x;
  const int lane = tid & 63;
  const int wave = tid >> 6;
  const int wm = wave >> 1, wn = wave & 1;

  const int nbn = N / BN;
  const int nwg = (2048 / BM) * nbn;
  const int bidx = (int)blockIdx.x;
  const int wgid = (bidx & 7) * (nwg >> 3) + (bidx >> 3);
  const int bm = wgid / nbn;
  const int bn = wgid % nbn;

  const int srow = tid >> 2;
  const int scolL = (tid & 3) << 3;
  const int scolG = scolL ^ ((srow & 6) << 2);
  const unsigned short* gA = A + (size_t)(bm * BM + srow) * K + scolG;
  const unsigned short* gB = Bt + (size_t)(bn * BN + srow) * K + scolG;
  const int sstage = srow * 32 + scolL;
  const size_t rstep = (size_t)SROWS * K;

  const int fr = lane & 15;
  const int fko = ((lane >> 4) << 3) ^ ((lane & 6) << 2);
  const int aoff = (wm * 64 + fr) * 32 + fko;
  const int boff = ASLAB + (wn * 64 + fr) * 32 + fko;

  f32x4 acc[4][4] = {};

#pragma unroll
  for (int t = 0; t < 3; ++t) {
    const unsigned short* sA = gA + t * 32;
    const unsigned short* sB = gB + t * 32;
    unsigned short* dst = lds + t * BUF;
    gload16(sA,         dst + sstage);
    gload16(sA + rstep, dst + sstage + SROWS * 32);
    gload16(sB,         dst + ASLAB + sstage);
    gload16(sB + rstep, dst + ASLAB + sstage + SROWS * 32);
  }
  asm volatile("s_waitcnt vmcnt(8)" ::: "memory");
  __builtin_amdgcn_s_barrier();

  for (int v = 0; v < NT; ++v) {
    const int rb = (v & 3) * BUF;
    const int wb = ((v + 3) & 3) * BUF;
    const int tn = (v + 3) & (NT - 1);
    const unsigned short* srcA = gA + tn * 32;
    const unsigned short* srcB = gB + tn * 32;

    bf16x8 af[4], bfv[4];
#pragma unroll
    for (int mi = 0; mi < 4; ++mi)
      af[mi] = *(const bf16x8*)(lds + rb + aoff + mi * 512);
#pragma unroll
    for (int ni = 0; ni < 4; ++ni)
      bfv[ni] = *(const bf16x8*)(lds + rb + boff + ni * 512);

    gload16(srcA,         lds + wb + sstage);
    gload16(srcA + rstep, lds + wb + sstage + SROWS * 32);
    gload16(srcB,         lds + wb + ASLAB + sstage);
    gload16(srcB + rstep, lds + wb + ASLAB + sstage + SROWS * 32);

    __builtin_amdgcn_s_setprio(1);
#pragma unroll
    for (int mi = 0; mi < 4; ++mi)
#pragma unroll
      for (int ni = 0; ni < 4; ++ni)
        acc[mi][ni] = __builtin_amdgcn_mfma_f32_16x16x32_bf16(af[mi], bfv[ni], acc[mi][ni], 0, 0, 0);
    __builtin_amdgcn_s_setprio(0);

    asm volatile("s_waitcnt vmcnt(8)" ::: "memory");
    __builtin_amdgcn_s_barrier();
  }

  const int fq = lane >> 4;
#pragma unroll
  for (int mi = 0; mi < 4; ++mi)
#pragma unroll
    for (int ni = 0; ni < 4; ++ni)
#pragma unroll
      for (int ii = 0; ii < 4; ++ii) {
        const int r = bm * BM + wm * 64 + mi * 16 + fq * 4 + ii;
        const int c = bn * BN + wn * 64 + ni * 16 + fr;
        C[(size_t)r * N + c] = f2bf(acc[mi][ni][ii]);
      }
}

// ---------- combine dot partials + per-chunk V sums (raw sums to chks) ----------
__global__ void scan_chunks2(const float* __restrict__ dotP,
                             const unsigned short* __restrict__ v,
                             float* __restrict__ dotb,
                             float* __restrict__ chks) {
  __shared__ float dt[CHUNK];
  const int bid = blockIdx.x;          // bh*NCHUNK + c
  const int c = bid & (NCHUNK - 1);
  const int bh = bid >> 5;
  const int b = bh >> 4, h = bh & 15;
  const int d = threadIdx.x;           // 128
  const int t0 = c * CHUNK;

  const size_t di = (size_t)bh * Tc + t0 + d;
  float dv = dotP[di] + dotP[(size_t)BHT + di];
  dt[d] = dv;
  dotb[di] = dv;
  __syncthreads();

  const unsigned short* vp = v + ((size_t)(b * Tc + t0)) * Dc + h * HDc + d;
  float acc = 0.f;
  for (int t = 0; t < CHUNK; ++t)
    acc += dt[t] * bf2f(vp[(size_t)t * Dc]);
  chks[(size_t)bid * HDc + d] = acc;
}

// ---------- final: exclusive prefix of chunk sums (in-block) + cumsum/divide ----
__global__ void scan_final(const float* __restrict__ dotb,
                           const unsigned short* __restrict__ v,
                           const unsigned short* __restrict__ kp,
                           const float* __restrict__ chks,
                           unsigned short* __restrict__ attn) {
  int bid = blockIdx.x;
  int c = bid % NCHUNK, bh = bid / NCHUNK;
  int b = bh / Hc, h = bh % Hc;
  int d = threadIdx.x;
  float acc = 0.f;
  for (int cc = 0; cc < c; ++cc)
    acc += chks[((size_t)bh * NCHUNK + cc) * HDc + d];
  const float* dp = dotb + (size_t)bh * Tc + c * CHUNK;
  size_t base = ((size_t)(b * Tc + c * CHUNK)) * Dc + h * HDc + d;
  for (int t = 0; t < CHUNK; ++t) {
    size_t idx = base + (size_t)t * Dc;
    acc += dp[t] * bf2f(v[idx]);
    attn[idx] = f2bf(acc / bf2f(kp[idx]));
  }
}

// ---------- launch ----------
extern "C" void kernel_launch(void* const* d_in, const int* in_sizes, int n_in,
                              void* d_out, int out_size, void* d_ws, size_t ws_size,
                              hipStream_t stream) {
  const float* hs = (const float*)d_in[0];
  const float* Wq = (const float*)d_in[1];
  const float* Wk = (const float*)d_in[2];
  const float* Wv = (const float*)d_in[3];
  const float* Wo = (const float*)d_in[4];
  const float* Fq = (const float*)d_in[5];
  const float* Fk = (const float*)d_in[6];
  float* out = (float*)d_out;

  const size_t MD = (size_t)Mrows * Dc;  // 16,777,216
  const size_t DD = (size_t)Dc * Dc;     // 4,194,304

  char* w = (char*)d_ws;
  size_t off = 0;
  auto take = [&](size_t bytes) -> void* {
    void* r = w + off;
    off += (bytes + 255) & ~(size_t)255;
    return r;
  };

  unsigned short* hs_bf = (unsigned short*)take(MD * 2);  // reused as attnbf
  unsigned short* wq_bf = (unsigned short*)take(DD * 2);
  unsigned short* wtfq  = (unsigned short*)take(DD * 2);
  unsigned short* wk_bf = (unsigned short*)take(DD * 2);
  unsigned short* wtfk  = (unsigned short*)take(DD * 2);
  unsigned short* wcat  = (unsigned short*)take(3 * DD * 2);  // [Wsum^T|Wkf^T|Wv^T]
  unsigned short* wto   = (unsigned short*)take(DD * 2);
  unsigned short* Kp    = (unsigned short*)take(MD * 2);
  unsigned short* Vbf   = (unsigned short*)take(MD * 2);
  float* dotP = (float*)take((size_t)2 * BHT * 4);
  float* dotb = (float*)take((size_t)BHT * 4);
  float* chks = (float*)take((size_t)Bc * Hc * NCHUNK * HDc * 4);

  unsigned short* attnbf = hs_bf;    // hs_bf dead after fused SKV GEMM

  const float OFF = (float)(-0.5 * log(2048.0) + 1e-6);

  // allow dynamic LDS (defensive; ignore errors)
  (void)hipFuncSetAttribute((const void*)gemm8<0>, hipFuncAttributeMaxDynamicSharedMemorySize, 131072);
  (void)hipFuncSetAttribute((const void*)gemm8<5>, hipFuncAttributeMaxDynamicSharedMemorySize, 131072);
  (void)hipFuncSetAttribute((const void*)gemmW,    hipFuncAttributeMaxDynamicSharedMemorySize, 65536);

  // 1) convert hidden states
  cvt_bf16<<<(int)(MD / 1024), 256, 0, stream>>>(hs, hs_bf);

  // 2) fused weight prep: transposes (Fq,Fk,Wv,Wo) + plain cvts (Wq,Wk)
  prep6<<<dim3(Dc / 32, Dc / 32, 6), 256, 0, stream>>>(
      Fq, wtfq, Fk, wtfk, Wv, wcat + 2 * DD, Wo, wto, Wq, wq_bf, Wk, wk_bf);

  // 3) weight products (z-batched, 128^2 tiles, ring-4 = 64KB LDS):
  //    wcat[0:DD) = (Wq@Fq)^T ; wcat[DD:2DD) = (Wk@Fk)^T
  gemmW<<<dim3(256, 2), 256, 65536, stream>>>(
      wtfq, wq_bf, wcat, wtfk, wk_bf, wcat + DD);

  // 3b) Wsum^T = Wqf^T + Wkf^T (in place over wcat[0:DD))
  add_bf16<<<(int)(DD / 2048), 256, 0, stream>>>(wcat, wcat + DD);

  // 4) fused SKV GEMM: hs @ [Wsum|Wkf|Wv] ->
  //    seg0: per-head dot partials (dotP), seg1: K'=exp (Kp), seg2: V (Vbf)
  const int fblocks = (Mrows / 256) * (6144 / 256);  // 768
  gemm8<5><<<fblocks, 512, 131072, stream>>>(
      hs_bf, wcat, dotP, Kp, Vbf, Mrows, 6144, Dc, Dc, OFF);

  // 5) combine dot partials + per-chunk V sums (raw chunk sums)
  scan_chunks2<<<Bc * Hc * NCHUNK, 128, 0, stream>>>(dotP, Vbf, dotb, chks);

  // 6) final: in-block exclusive prefix + cumsum + divide -> bf16 attn
  scan_final<<<Bc * Hc * NCHUNK, 128, 0, stream>>>(dotb, Vbf, Kp, chks, attnbf);

  // 7) output projection (fp32 out)
  const int gblocks = (Mrows / 256) * (Dc / 256);  // 256
  gemm8<0><<<gblocks, 512, 131072, stream>>>(
      attnbf, wto, out, nullptr, nullptr, Mrows, Dc, Dc, Dc, 0.f);
}